// Round 5
// baseline (50.585 us; speedup 1.0000x reference)
//
#include <hip/hip_runtime.h>
#include <hip/hip_bf16.h>
#include <stdint.h>

// Problem constants (B,S,D,K) = (2,4096,512,32)
#define S_LEN  4096
#define D_DIM  512
#define K_R    32
#define M_ROWS 8192

typedef __attribute__((ext_vector_type(8))) short bf16x8;
typedef __attribute__((ext_vector_type(4))) float f32x4;

__device__ __forceinline__ float bf2f(short u) {
  union { unsigned int i; float f; } c;
  c.i = ((unsigned int)(unsigned short)u) << 16;
  return c.f;
}

__device__ __forceinline__ void gload_lds16(const void* g, void* lds) {
  __builtin_amdgcn_global_load_lds(
      (__attribute__((address_space(1))) void*)g,
      (__attribute__((address_space(3))) void*)lds, 16, 0, 0);
}

__device__ __forceinline__ int4 pack8(float4 v0, float4 v1) {
  union { __hip_bfloat16 h[8]; int4 v; } u;
  u.h[0] = __float2bfloat16(v0.x); u.h[1] = __float2bfloat16(v0.y);
  u.h[2] = __float2bfloat16(v0.z); u.h[3] = __float2bfloat16(v0.w);
  u.h[4] = __float2bfloat16(v1.x); u.h[5] = __float2bfloat16(v1.y);
  u.h[6] = __float2bfloat16(v1.z); u.h[7] = __float2bfloat16(v1.w);
  return u.v;
}

#define BM 128
#define BN 64
#define BK 64

// ---------------------------------------------------------------------------
// Kernel 1: blocks [0,32): wcgemm  WcT[j][i] = sum_p Wout[p][j] * Win[i][p]
//             reading RAW f32 weights with fused transpose-cast staging into
//             the XOR-swizzled LDS layout (stored unit = logical ^ (row&7)).
//           blocks [32,2080): cast x -> bf16 (Xb).
// ---------------------------------------------------------------------------
__global__ void __launch_bounds__(256) prep_wc_kernel(
    const float* __restrict__ x, __hip_bfloat16* __restrict__ xb,
    const float* __restrict__ Win, const float* __restrict__ Wout,
    __hip_bfloat16* __restrict__ WcT) {
  __shared__ __hip_bfloat16 As[BM][BK];   // 16 KB
  __shared__ __hip_bfloat16 Bs[BN][BK];   //  8 KB
  const int tid = threadIdx.x;

  if (blockIdx.x >= 32) {
    // ---- x cast path ----
    const int i = (blockIdx.x - 32) * 256 + tid;
    const float4* xp = (const float4*)x;
    ((int4*)xb)[i] = pack8(xp[2 * i], xp[2 * i + 1]);
    return;
  }

  // ---- wcgemm path ----
  const int id2 = blockIdx.x;           // [0,32)
  const int bm0 = (id2 >> 3) * BM;      // j base
  const int bn0 = (id2 & 7) * BN;       // i base
  const int w = tid >> 6, l = tid & 63;
  const int wr  = (w >> 1) * 64;
  const int wcn = (w & 1) * 32;
  const int fr = l & 15, fq = l >> 4;

  f32x4 acc[4][2] = {};
  for (int k0 = 0; k0 < D_DIM; k0 += BK) {
    __syncthreads();   // previous iter's readers done
    // A-stage: As[j][p] <- Wout[k0+p][bm0+j]   (transpose-cast)
#pragma unroll
    for (int it = 0; it < 4; ++it) {
      const int task = it * 256 + tid;        // [0,1024)
      const int jq = (task & 31) * 4;         // j quad
      const int pp = (task >> 5) * 2;         // even p pair [0,64)
      const float4 fa = *(const float4*)&Wout[(size_t)(k0 + pp) * 512 + bm0 + jq];
      const float4 fb = *(const float4*)&Wout[(size_t)(k0 + pp + 1) * 512 + bm0 + jq];
      const float a_[4] = {fa.x, fa.y, fa.z, fa.w};
      const float b_[4] = {fb.x, fb.y, fb.z, fb.w};
#pragma unroll
      for (int t = 0; t < 4; ++t) {
        const int j = jq + t;
        union { __hip_bfloat16 h[2]; unsigned int u32; } pk;
        pk.h[0] = __float2bfloat16(a_[t]);
        pk.h[1] = __float2bfloat16(b_[t]);
        // stored unit = (pp>>3) ^ (j&7); byte-in-unit = (pp&7)*2
        char* dst = (char*)&As[0][0] + j * 128 +
                    (((pp >> 3) ^ (j & 7)) * 16) + (pp & 7) * 2;
        *(unsigned int*)dst = pk.u32;
      }
    }
    // B-stage: Bs[i][p] <- Win[bn0+i][k0+p]   (cast, pack8, swizzled b128)
#pragma unroll
    for (int it = 0; it < 2; ++it) {
      const int task = it * 256 + tid;   // [0,512)
      const int i = task >> 3;           // [0,64)
      const int u = task & 7;
      const float4 f0 = *(const float4*)&Win[(size_t)(bn0 + i) * 512 + k0 + u * 8];
      const float4 f1 = *(const float4*)&Win[(size_t)(bn0 + i) * 512 + k0 + u * 8 + 4];
      const int4 pk = pack8(f0, f1);
      char* dst = (char*)&Bs[0][0] + i * 128 + ((u ^ (i & 7)) * 16);
      *(int4*)dst = pk;
    }
    __syncthreads();
#pragma unroll
    for (int kk = 0; kk < 2; ++kk) {
      const int u = (kk * 4 + fq) ^ (fr & 7);
      bf16x8 af[4], bfv[2];
#pragma unroll
      for (int m = 0; m < 4; ++m)
        af[m] = *(const bf16x8*)&As[wr + m * 16 + fr][u * 8];
#pragma unroll
      for (int n = 0; n < 2; ++n)
        bfv[n] = *(const bf16x8*)&Bs[wcn + n * 16 + fr][u * 8];
#pragma unroll
      for (int m = 0; m < 4; ++m)
#pragma unroll
        for (int n = 0; n < 2; ++n)
          acc[m][n] = __builtin_amdgcn_mfma_f32_16x16x32_bf16(af[m], bfv[n], acc[m][n], 0, 0, 0);
    }
  }
#pragma unroll
  for (int m = 0; m < 4; ++m)
#pragma unroll
    for (int n = 0; n < 2; ++n)
#pragma unroll
      for (int r = 0; r < 4; ++r) {
        const int grow = bm0 + wr + m * 16 + fq * 4 + r;
        const int gcol = bn0 + wcn + n * 16 + fr;
        WcT[(size_t)grow * D_DIM + gcol] = __float2bfloat16(acc[m][n][r]);
      }
}

// ---------------------------------------------------------------------------
// Kernel 2: Y = Xb @ Wc   (M=8192, N=512, K=512), bf16 out.
//   2-phase double-buffered LDS, proven structure from R4.
// ---------------------------------------------------------------------------
__global__ void __launch_bounds__(256) gemm_y_kernel(
    const __hip_bfloat16* __restrict__ A,    // Xb (M x 512)
    const __hip_bfloat16* __restrict__ BT,   // WcT (n x k)
    __hip_bfloat16* __restrict__ Y) {
  __shared__ __hip_bfloat16 As[2][BM][BK];   // 32 KB
  __shared__ __hip_bfloat16 Bs[2][BN][BK];   // 16 KB
  const int tid = threadIdx.x;
  const int w = tid >> 6, l = tid & 63;

  const int lin = blockIdx.x;
  const int id2 = (lin & 7) * 64 + (lin >> 3);
  const int bm0 = (id2 >> 3) * BM;
  const int bn0 = (id2 & 7) * BN;

  const int wr  = (w >> 1) * 64;
  const int wcn = (w & 1) * 32;

  const int rin = l >> 3;
  const int usw = (l & 7) ^ rin;
  const __hip_bfloat16* gA = A + (size_t)(bm0 + w * 8 + rin) * D_DIM + usw * 8;
  const __hip_bfloat16* gB = BT + (size_t)(bn0 + w * 8 + rin) * D_DIM + usw * 8;

  const int fr = l & 15, fq = l >> 4;
  f32x4 acc[4][2] = {};

#define STAGE(buf, k0)                                                          \
  {                                                                             \
    _Pragma("unroll")                                                           \
    for (int i = 0; i < 4; ++i)                                                 \
      gload_lds16(gA + (size_t)(i * 32) * D_DIM + (k0),                         \
                  &As[buf][w * 8][0] + i * 32 * BK);                            \
    _Pragma("unroll")                                                           \
    for (int j = 0; j < 2; ++j)                                                 \
      gload_lds16(gB + (size_t)(j * 32) * D_DIM + (k0),                         \
                  &Bs[buf][w * 8][0] + j * 32 * BK);                            \
  }

#define COMPUTE(buf)                                                            \
  {                                                                             \
    _Pragma("unroll")                                                           \
    for (int kk = 0; kk < 2; ++kk) {                                            \
      const int u = (kk * 4 + fq) ^ (fr & 7);                                   \
      bf16x8 af[4], bfv[2];                                                     \
      _Pragma("unroll")                                                         \
      for (int m = 0; m < 4; ++m)                                               \
        af[m] = *(const bf16x8*)&As[buf][wr + m * 16 + fr][u * 8];              \
      _Pragma("unroll")                                                         \
      for (int n = 0; n < 2; ++n)                                               \
        bfv[n] = *(const bf16x8*)&Bs[buf][wcn + n * 16 + fr][u * 8];            \
      _Pragma("unroll")                                                         \
      for (int m = 0; m < 4; ++m)                                               \
        _Pragma("unroll")                                                       \
        for (int n = 0; n < 2; ++n)                                             \
          acc[m][n] = __builtin_amdgcn_mfma_f32_16x16x32_bf16(                  \
              af[m], bfv[n], acc[m][n], 0, 0, 0);                               \
    }                                                                           \
  }

  STAGE(0, 0);
  __syncthreads();
  int cur = 0;
#pragma unroll
  for (int t = 0; t < 7; ++t) {
    STAGE(cur ^ 1, (t + 1) * BK);
    COMPUTE(cur);
    __syncthreads();
    cur ^= 1;
  }
  COMPUTE(cur);
#undef STAGE
#undef COMPUTE

#pragma unroll
  for (int m = 0; m < 4; ++m)
#pragma unroll
    for (int n = 0; n < 2; ++n)
#pragma unroll
      for (int r = 0; r < 4; ++r) {
        const int grow = bm0 + wr + m * 16 + fq * 4 + r;
        const int gcol = bn0 + wcn + n * 16 + fr;
        Y[(size_t)grow * D_DIM + gcol] = __float2bfloat16(acc[m][n][r]);
      }
}

// ---------------------------------------------------------------------------
// Kernel 3: out[row,:] = x[row,:] + b_out + sum_k w[s,k] * Y[b, routes[s,k], :]
//   4 waves/block, one row per wave, lane owns 8 cols. XCD-chunked rows.
// ---------------------------------------------------------------------------
__global__ void __launch_bounds__(256) gather_out_kernel(
    const __hip_bfloat16* __restrict__ Y,
    const float* __restrict__ x,
    const float* __restrict__ b_out,
    const float* __restrict__ fw,
    const int* __restrict__ routes,
    float* __restrict__ out) {
  __shared__ float w_s[4][K_R];
  __shared__ int   r_s[4][K_R];
  const int tid = threadIdx.x;
  const int w = tid >> 6, l = tid & 63;
  const int lin = blockIdx.x;                      // 2048 blocks
  const int bchunk = (lin & 7) * 256 + (lin >> 3); // XCD-contiguous rows
  const int row = bchunk * 4 + w;
  const int s = row & (S_LEN - 1);
  const int b = row >> 12;
  if (l < K_R) {
    r_s[w][l] = routes[s * K_R + l];
    w_s[w][l] = fw[s * K_R + l];
  }
  __syncthreads();
  const __hip_bfloat16* yb = Y + (size_t)b * S_LEN * D_DIM + l * 8;
  float acc[8] = {};
#pragma unroll 8
  for (int k = 0; k < K_R; ++k) {
    const float wk = w_s[w][k];
    const bf16x8 v = *(const bf16x8*)(yb + (size_t)r_s[w][k] * D_DIM);
#pragma unroll
    for (int j = 0; j < 8; ++j) acc[j] = fmaf(wk, bf2f(v[j]), acc[j]);
  }
  const size_t base = (size_t)row * D_DIM + l * 8;
  const float4 x0 = *(const float4*)&x[base];
  const float4 x1 = *(const float4*)&x[base + 4];
  const float4 b0 = *(const float4*)&b_out[l * 8];
  const float4 b1 = *(const float4*)&b_out[l * 8 + 4];
  float4 o0, o1;
  o0.x = x0.x + b0.x + acc[0]; o0.y = x0.y + b0.y + acc[1];
  o0.z = x0.z + b0.z + acc[2]; o0.w = x0.w + b0.w + acc[3];
  o1.x = x1.x + b1.x + acc[4]; o1.y = x1.y + b1.y + acc[5];
  o1.z = x1.z + b1.z + acc[6]; o1.w = x1.w + b1.w + acc[7];
  *(float4*)&out[base]     = o0;
  *(float4*)&out[base + 4] = o1;
}

// ---------------------------------------------------------------------------
extern "C" void kernel_launch(void* const* d_in, const int* in_sizes, int n_in,
                              void* d_out, int out_size, void* d_ws, size_t ws_size,
                              hipStream_t stream) {
  const float* x      = (const float*)d_in[0];
  const float* W_in   = (const float*)d_in[1];
  const float* W_out  = (const float*)d_in[2];
  const float* b_out  = (const float*)d_in[3];
  const float* fw     = (const float*)d_in[4];
  const int*   routes = (const int*)d_in[5];
  float* out = (float*)d_out;

  // workspace: Xb(8MB) | WcT(512KB) | Y(8MB)
  char* ws = (char*)d_ws;
  __hip_bfloat16* Xb  = (__hip_bfloat16*)ws;
  __hip_bfloat16* WcT = (__hip_bfloat16*)(ws + 8388608);
  __hip_bfloat16* Y   = (__hip_bfloat16*)(ws + 8912896);

  // 1) wcgemm from raw f32 weights (32 blocks, first) || x cast (2048 blocks)
  prep_wc_kernel<<<2080, 256, 0, stream>>>(x, Xb, W_in, W_out, WcT);
  // 2) Y = Xb @ Wc  (bf16 out)
  gemm_y_kernel<<<512, 256, 0, stream>>>(Xb, WcT, Y);
  // 3) out = x + b_out + gather-fuse(Y)
  gather_out_kernel<<<2048, 256, 0, stream>>>(Y, x, b_out, fw, routes, out);
}

// Round 6
// 44.950 us; speedup vs baseline: 1.1254x; 1.1254x over previous
//
#include <hip/hip_runtime.h>
#include <hip/hip_bf16.h>
#include <stdint.h>

// Problem constants (B,S,D,K) = (2,4096,512,32)
#define S_LEN  4096
#define D_DIM  512
#define K_R    32
#define M_ROWS 8192

typedef __attribute__((ext_vector_type(8))) short bf16x8;
typedef __attribute__((ext_vector_type(4))) float f32x4;

__device__ __forceinline__ float bf2f(short u) {
  union { unsigned int i; float f; } c;
  c.i = ((unsigned int)(unsigned short)u) << 16;
  return c.f;
}

__device__ __forceinline__ void gload_lds16(const void* g, void* lds) {
  __builtin_amdgcn_global_load_lds(
      (__attribute__((address_space(1))) void*)g,
      (__attribute__((address_space(3))) void*)lds, 16, 0, 0);
}

__device__ __forceinline__ int4 pack8(float4 v0, float4 v1) {
  union { __hip_bfloat16 h[8]; int4 v; } u;
  u.h[0] = __float2bfloat16(v0.x); u.h[1] = __float2bfloat16(v0.y);
  u.h[2] = __float2bfloat16(v0.z); u.h[3] = __float2bfloat16(v0.w);
  u.h[4] = __float2bfloat16(v1.x); u.h[5] = __float2bfloat16(v1.y);
  u.h[6] = __float2bfloat16(v1.z); u.h[7] = __float2bfloat16(v1.w);
  return u.v;
}

#define BM 128
#define BN 64
#define BK 64

// ---------------------------------------------------------------------------
// Kernel 1 (prep): blocks [0,2048): cast x->bf16.
//                  blocks [2048,2112): cast W_in->bf16 (Winb).
//                  blocks [2112,2176): transpose-cast W_out -> WoutTb.
//   (R4-proven implementation, verbatim.)
// ---------------------------------------------------------------------------
__global__ void __launch_bounds__(256) prep_kernel(
    const float* __restrict__ x, __hip_bfloat16* __restrict__ xb,
    const float* __restrict__ Win, __hip_bfloat16* __restrict__ Winb,
    const float* __restrict__ Wout, __hip_bfloat16* __restrict__ WoutTb) {
  __shared__ __hip_bfloat16 Lds[64][66];   // stride 66 -> conflict-free cols
  const int tid = threadIdx.x;
  if (blockIdx.x < 2048) {
    const int i = blockIdx.x * 256 + tid;
    const float4* xp = (const float4*)x;
    ((int4*)xb)[i] = pack8(xp[2 * i], xp[2 * i + 1]);
    return;
  }
  if (blockIdx.x < 2112) {   // Win cast: 64 blocks x 256 thr x 16 elems
    const int e4 = ((blockIdx.x - 2048) * 256 + tid) * 4;  // in float4 units
    const float4* wp = (const float4*)Win;
    int4* op = (int4*)Winb;
#pragma unroll
    for (int h = 0; h < 2; ++h)
      op[e4 / 2 + h] = pack8(wp[e4 + 2 * h], wp[e4 + 2 * h + 1]);
    return;
  }
  // transpose-cast: 64 blocks, 64x64 tile.  WoutTb[j][i] = Wout[i][j]
  const int bx = blockIdx.x - 2112;
  const int tr = (bx >> 3) * 64;   // row base in Wout
  const int tc = (bx & 7) * 64;    // col base in Wout
#pragma unroll
  for (int it = 0; it < 4; ++it) {
    const int id = it * 256 + tid;          // [0,1024)
    const int r = id >> 4, c4 = (id & 15) * 4;
    const float4 v = *(const float4*)&Wout[(size_t)(tr + r) * 512 + tc + c4];
    Lds[r][c4]     = __float2bfloat16(v.x);
    Lds[r][c4 + 1] = __float2bfloat16(v.y);
    Lds[r][c4 + 2] = __float2bfloat16(v.z);
    Lds[r][c4 + 3] = __float2bfloat16(v.w);
  }
  __syncthreads();
#pragma unroll
  for (int it = 0; it < 2; ++it) {
    const int id = it * 256 + tid;          // [0,512)
    const int j = id >> 3, i0 = (id & 7) * 8;
    union { __hip_bfloat16 h[8]; int4 v; } u;
#pragma unroll
    for (int r = 0; r < 8; ++r) u.h[r] = Lds[i0 + r][j];
    *(int4*)&WoutTb[(size_t)(tc + j) * 512 + tr + i0] = u.v;
  }
}

// ---------------------------------------------------------------------------
// Kernel 2 (wc): WcT[j][q] = sum_p WoutTb[j][p] * Winb[q][p]  (bf16 out)
//   R4 mid-kernel's wcgemm path, standalone, 32 blocks.
// ---------------------------------------------------------------------------
__global__ void __launch_bounds__(256) wc_kernel(
    const __hip_bfloat16* __restrict__ WoutTb,   // A  (m=j, k=p)
    const __hip_bfloat16* __restrict__ Winb,     // BT (n=q, k=p)
    __hip_bfloat16* __restrict__ WcT) {
  __shared__ __hip_bfloat16 As[BM][BK];   // 16 KB
  __shared__ __hip_bfloat16 Bs[BN][BK];   //  8 KB
  const int tid = threadIdx.x;
  const int w = tid >> 6, l = tid & 63;

  const int id2 = blockIdx.x;           // [0,32)
  const int bm0 = (id2 >> 3) * BM;      // 4 m-tiles (j)
  const int bn0 = (id2 & 7) * BN;       // 8 n-tiles (q)
  const int wr  = (w >> 1) * 64;
  const int wcn = (w & 1) * 32;

  const int rin = l >> 3;
  const int usw = (l & 7) ^ rin;
  const __hip_bfloat16* gA = WoutTb + (size_t)(bm0 + w * 8 + rin) * D_DIM + usw * 8;
  const __hip_bfloat16* gB = Winb   + (size_t)(bn0 + w * 8 + rin) * D_DIM + usw * 8;
  __hip_bfloat16* ldsA = &As[w * 8][0];
  __hip_bfloat16* ldsB = &Bs[w * 8][0];
  const int fr = l & 15, fq = l >> 4;

  f32x4 acc[4][2] = {};
  for (int k0 = 0; k0 < D_DIM; k0 += BK) {
#pragma unroll
    for (int i = 0; i < 4; ++i)
      gload_lds16(gA + (size_t)(i * 32) * D_DIM + k0, ldsA + i * 32 * BK);
#pragma unroll
    for (int j = 0; j < 2; ++j)
      gload_lds16(gB + (size_t)(j * 32) * D_DIM + k0, ldsB + j * 32 * BK);
    __syncthreads();
#pragma unroll
    for (int kk = 0; kk < 2; ++kk) {
      const int u = (kk * 4 + fq) ^ (fr & 7);
      bf16x8 af[4], bfv[2];
#pragma unroll
      for (int m = 0; m < 4; ++m)
        af[m] = *(const bf16x8*)&As[wr + m * 16 + fr][u * 8];
#pragma unroll
      for (int n = 0; n < 2; ++n)
        bfv[n] = *(const bf16x8*)&Bs[wcn + n * 16 + fr][u * 8];
#pragma unroll
      for (int m = 0; m < 4; ++m)
#pragma unroll
        for (int n = 0; n < 2; ++n)
          acc[m][n] = __builtin_amdgcn_mfma_f32_16x16x32_bf16(af[m], bfv[n], acc[m][n], 0, 0, 0);
    }
    __syncthreads();
  }
#pragma unroll
  for (int m = 0; m < 4; ++m)
#pragma unroll
    for (int n = 0; n < 2; ++n)
#pragma unroll
      for (int r = 0; r < 4; ++r) {
        const int grow = bm0 + wr + m * 16 + fq * 4 + r;
        const int gcol = bn0 + wcn + n * 16 + fr;
        WcT[(size_t)grow * D_DIM + gcol] = __float2bfloat16(acc[m][n][r]);
      }
}

// ---------------------------------------------------------------------------
// Kernel 3: Y = Xb @ Wc   (M=8192, N=512, K=512), bf16 out.
//   2-phase double-buffered LDS, proven structure from R4.
// ---------------------------------------------------------------------------
__global__ void __launch_bounds__(256) gemm_y_kernel(
    const __hip_bfloat16* __restrict__ A,    // Xb (M x 512)
    const __hip_bfloat16* __restrict__ BT,   // WcT (n x k)
    __hip_bfloat16* __restrict__ Y) {
  __shared__ __hip_bfloat16 As[2][BM][BK];   // 32 KB
  __shared__ __hip_bfloat16 Bs[2][BN][BK];   // 16 KB
  const int tid = threadIdx.x;
  const int w = tid >> 6, l = tid & 63;

  const int lin = blockIdx.x;
  const int id2 = (lin & 7) * 64 + (lin >> 3);
  const int bm0 = (id2 >> 3) * BM;
  const int bn0 = (id2 & 7) * BN;

  const int wr  = (w >> 1) * 64;
  const int wcn = (w & 1) * 32;

  const int rin = l >> 3;
  const int usw = (l & 7) ^ rin;
  const __hip_bfloat16* gA = A + (size_t)(bm0 + w * 8 + rin) * D_DIM + usw * 8;
  const __hip_bfloat16* gB = BT + (size_t)(bn0 + w * 8 + rin) * D_DIM + usw * 8;

  const int fr = l & 15, fq = l >> 4;
  f32x4 acc[4][2] = {};

#define STAGE(buf, k0)                                                          \
  {                                                                             \
    _Pragma("unroll")                                                           \
    for (int i = 0; i < 4; ++i)                                                 \
      gload_lds16(gA + (size_t)(i * 32) * D_DIM + (k0),                         \
                  &As[buf][w * 8][0] + i * 32 * BK);                            \
    _Pragma("unroll")                                                           \
    for (int j = 0; j < 2; ++j)                                                 \
      gload_lds16(gB + (size_t)(j * 32) * D_DIM + (k0),                         \
                  &Bs[buf][w * 8][0] + j * 32 * BK);                            \
  }

#define COMPUTE(buf)                                                            \
  {                                                                             \
    _Pragma("unroll")                                                           \
    for (int kk = 0; kk < 2; ++kk) {                                            \
      const int u = (kk * 4 + fq) ^ (fr & 7);                                   \
      bf16x8 af[4], bfv[2];                                                     \
      _Pragma("unroll")                                                         \
      for (int m = 0; m < 4; ++m)                                               \
        af[m] = *(const bf16x8*)&As[buf][wr + m * 16 + fr][u * 8];              \
      _Pragma("unroll")                                                         \
      for (int n = 0; n < 2; ++n)                                               \
        bfv[n] = *(const bf16x8*)&Bs[buf][wcn + n * 16 + fr][u * 8];            \
      _Pragma("unroll")                                                         \
      for (int m = 0; m < 4; ++m)                                               \
        _Pragma("unroll")                                                       \
        for (int n = 0; n < 2; ++n)                                             \
          acc[m][n] = __builtin_amdgcn_mfma_f32_16x16x32_bf16(                  \
              af[m], bfv[n], acc[m][n], 0, 0, 0);                               \
    }                                                                           \
  }

  STAGE(0, 0);
  __syncthreads();
  int cur = 0;
#pragma unroll
  for (int t = 0; t < 7; ++t) {
    STAGE(cur ^ 1, (t + 1) * BK);
    COMPUTE(cur);
    __syncthreads();
    cur ^= 1;
  }
  COMPUTE(cur);
#undef STAGE
#undef COMPUTE

#pragma unroll
  for (int m = 0; m < 4; ++m)
#pragma unroll
    for (int n = 0; n < 2; ++n)
#pragma unroll
      for (int r = 0; r < 4; ++r) {
        const int grow = bm0 + wr + m * 16 + fq * 4 + r;
        const int gcol = bn0 + wcn + n * 16 + fr;
        Y[(size_t)grow * D_DIM + gcol] = __float2bfloat16(acc[m][n][r]);
      }
}

// ---------------------------------------------------------------------------
// Kernel 4: out[row,:] = x[row,:] + b_out + sum_k w[s,k] * Y[b, routes[s,k], :]
//   4 waves/block, one row per wave, lane owns 8 cols. XCD-chunked rows.
// ---------------------------------------------------------------------------
__global__ void __launch_bounds__(256) gather_out_kernel(
    const __hip_bfloat16* __restrict__ Y,
    const float* __restrict__ x,
    const float* __restrict__ b_out,
    const float* __restrict__ fw,
    const int* __restrict__ routes,
    float* __restrict__ out) {
  __shared__ float w_s[4][K_R];
  __shared__ int   r_s[4][K_R];
  const int tid = threadIdx.x;
  const int w = tid >> 6, l = tid & 63;
  const int lin = blockIdx.x;                      // 2048 blocks
  const int bchunk = (lin & 7) * 256 + (lin >> 3); // XCD-contiguous rows
  const int row = bchunk * 4 + w;
  const int s = row & (S_LEN - 1);
  const int b = row >> 12;
  if (l < K_R) {
    r_s[w][l] = routes[s * K_R + l];
    w_s[w][l] = fw[s * K_R + l];
  }
  __syncthreads();
  const __hip_bfloat16* yb = Y + (size_t)b * S_LEN * D_DIM + l * 8;
  float acc[8] = {};
#pragma unroll 8
  for (int k = 0; k < K_R; ++k) {
    const float wk = w_s[w][k];
    const bf16x8 v = *(const bf16x8*)(yb + (size_t)r_s[w][k] * D_DIM);
#pragma unroll
    for (int j = 0; j < 8; ++j) acc[j] = fmaf(wk, bf2f(v[j]), acc[j]);
  }
  const size_t base = (size_t)row * D_DIM + l * 8;
  const float4 x0 = *(const float4*)&x[base];
  const float4 x1 = *(const float4*)&x[base + 4];
  const float4 b0 = *(const float4*)&b_out[l * 8];
  const float4 b1 = *(const float4*)&b_out[l * 8 + 4];
  float4 o0, o1;
  o0.x = x0.x + b0.x + acc[0]; o0.y = x0.y + b0.y + acc[1];
  o0.z = x0.z + b0.z + acc[2]; o0.w = x0.w + b0.w + acc[3];
  o1.x = x1.x + b1.x + acc[4]; o1.y = x1.y + b1.y + acc[5];
  o1.z = x1.z + b1.z + acc[6]; o1.w = x1.w + b1.w + acc[7];
  *(float4*)&out[base]     = o0;
  *(float4*)&out[base + 4] = o1;
}

// ---------------------------------------------------------------------------
extern "C" void kernel_launch(void* const* d_in, const int* in_sizes, int n_in,
                              void* d_out, int out_size, void* d_ws, size_t ws_size,
                              hipStream_t stream) {
  const float* x      = (const float*)d_in[0];
  const float* W_in   = (const float*)d_in[1];
  const float* W_out  = (const float*)d_in[2];
  const float* b_out  = (const float*)d_in[3];
  const float* fw     = (const float*)d_in[4];
  const int*   routes = (const int*)d_in[5];
  float* out = (float*)d_out;

  // workspace: Xb(8MB) | WcT(512KB) | Y(8MB) | Winb(512KB) | WoutTb(512KB)
  char* ws = (char*)d_ws;
  __hip_bfloat16* Xb     = (__hip_bfloat16*)ws;
  __hip_bfloat16* WcT    = (__hip_bfloat16*)(ws + 8388608);
  __hip_bfloat16* Y      = (__hip_bfloat16*)(ws + 8912896);
  __hip_bfloat16* Winb   = (__hip_bfloat16*)(ws + 17301504);
  __hip_bfloat16* WoutTb = (__hip_bfloat16*)(ws + 17825792);

  // 1) casts + transpose (elementwise, ~4.5us)
  prep_kernel<<<2176, 256, 0, stream>>>(x, Xb, W_in, Winb, W_out, WoutTb);
  // 2) WcT = WoutTb x Winb contraction (32 blocks, ~2.5us)
  wc_kernel<<<32, 256, 0, stream>>>(WoutTb, Winb, WcT);
  // 3) Y = Xb @ Wc (bf16 out, pure compute)
  gemm_y_kernel<<<512, 256, 0, stream>>>(Xb, WcT, Y);
  // 4) out = x + b_out + gather-fuse(Y)
  gather_out_kernel<<<2048, 256, 0, stream>>>(Y, x, b_out, fw, routes, out);
}